// Round 1
// baseline (157.613 us; speedup 1.0000x reference)
//
#include <hip/hip_runtime.h>

// OmniShift: out = a0*x + a1*dwconv1x1(x) + a2*dwconv3x3(x) + a3*dwconv5x5(x)
// Collapsed into ONE effective 5x5 depthwise conv per channel (all convs are
// cross-correlations in XLA, no kernel flip).
//
// x: (8, 192, 256, 256) fp32.  Memory-bound: ~805 MB min traffic -> ~128us floor.

constexpr int Bn = 8, Cn = 192, Hn = 256, Wn = 256;
constexpr int TR      = 32;        // output rows per block
constexpr int LROWS   = TR + 4;    // 36 staged rows (2-row halo each side)
constexpr int LSTRIDE = 260;       // 2 + 256 + 2 columns (left pad 2 => aligned b128 reads)
constexpr int BANDS   = Hn / TR;   // 8

__global__ __launch_bounds__(256, 4)
void omnishift_kernel(const float* __restrict__ x,
                      const float* __restrict__ w1,
                      const float* __restrict__ w3,
                      const float* __restrict__ w5,
                      const float* __restrict__ alpha,
                      float* __restrict__ out)
{
    __shared__ float lds[LROWS * LSTRIDE];   // 37440 B

    const int tid   = threadIdx.x;
    const int band  = blockIdx.x % BANDS;
    const int plane = blockIdx.x / BANDS;    // b*C + c
    const int c     = plane % Cn;
    const int r0    = band * TR;

    // ---- effective 5x5 weights (uniform across block -> broadcast loads) ----
    const float a0 = alpha[0], a1 = alpha[1], a2 = alpha[2], a3 = alpha[3];
    float wf[5][5];
#pragma unroll
    for (int i = 0; i < 5; ++i)
#pragma unroll
        for (int j = 0; j < 5; ++j) {
            float v = a3 * w5[(c * 5 + i) * 5 + j];
            if (i >= 1 && i <= 3 && j >= 1 && j <= 3)
                v += a2 * w3[(c * 3 + (i - 1)) * 3 + (j - 1)];
            if (i == 2 && j == 2)
                v += a1 * w1[c] + a0;
            wf[i][j] = v;
        }

    const float* xp = x + (size_t)plane * (Hn * Wn);

    // ---- zero the 4 halo columns of every staged row ----
    if (tid < LROWS * 4) {
        const int r   = tid >> 2;
        const int q   = tid & 3;
        const int col = (q < 2) ? q : (256 + q);   // 0,1,258,259
        lds[r * LSTRIDE + col] = 0.f;
    }

    // ---- stage interior: 36 rows x 256 floats, float4 global loads ----
    // LDS col = global col + 2
#pragma unroll
    for (int i = 0; i < 9; ++i) {
        const int fidx = tid + i * 256;      // 0..2303 = 36 rows * 64 float4
        const int row  = fidx >> 6;
        const int l    = fidx & 63;
        const int gr   = r0 - 2 + row;
        float4 v = make_float4(0.f, 0.f, 0.f, 0.f);
        if ((unsigned)gr < (unsigned)Hn)     // wave-uniform branch
            v = *reinterpret_cast<const float4*>(xp + gr * Wn + 4 * l);
        float* dst = &lds[row * LSTRIDE + 2 + 4 * l];   // byte off 8+16l: 8-aligned
        *reinterpret_cast<float2*>(dst)     = make_float2(v.x, v.y);
        *reinterpret_cast<float2*>(dst + 2) = make_float2(v.z, v.w);
    }
    __syncthreads();

    // ---- compute: thread = 4-col strip x 8 rows, 5x8 sliding register window ----
    const int ct     = tid & 63;     // column group: global cols 4*ct .. 4*ct+3
    const int rg     = tid >> 6;     // row group 0..3: block rows rg*8 .. rg*8+7
    const int oc0    = 4 * ct;       // LDS col base (== global col - 2 + 2)
    const int lrbase = rg * 8;

    float* outp = out + (size_t)plane * (Hn * Wn)
                      + (size_t)(r0 + rg * 8) * Wn + oc0;

    float win[5][8];
#pragma unroll
    for (int i = 0; i < 4; ++i) {
        const float* src = &lds[(lrbase + i) * LSTRIDE + oc0];  // 16B aligned
#pragma unroll
        for (int j = 0; j < 8; ++j) win[i][j] = src[j];
    }

#pragma unroll
    for (int k = 0; k < 8; ++k) {
        const float* src = &lds[(lrbase + 4 + k) * LSTRIDE + oc0];
#pragma unroll
        for (int j = 0; j < 8; ++j) win[4][j] = src[j];

        float o[4];
#pragma unroll
        for (int j = 0; j < 4; ++j) {
            float acc = 0.f;
#pragma unroll
            for (int i = 0; i < 5; ++i)
#pragma unroll
                for (int d = 0; d < 5; ++d)
                    acc += win[i][j + d] * wf[i][d];
            o[j] = acc;
        }
        *reinterpret_cast<float4*>(outp + (size_t)k * Wn) =
            make_float4(o[0], o[1], o[2], o[3]);

        // slide window down one row (full unroll -> register renaming, no movs)
#pragma unroll
        for (int i = 0; i < 4; ++i)
#pragma unroll
            for (int j = 0; j < 8; ++j) win[i][j] = win[i + 1][j];
    }
}

extern "C" void kernel_launch(void* const* d_in, const int* in_sizes, int n_in,
                              void* d_out, int out_size, void* d_ws, size_t ws_size,
                              hipStream_t stream)
{
    const float* x     = (const float*)d_in[0];
    const float* w1    = (const float*)d_in[1];
    const float* w3    = (const float*)d_in[2];
    const float* w5    = (const float*)d_in[3];
    const float* alpha = (const float*)d_in[4];
    float* out = (float*)d_out;

    const int grid = Bn * Cn * BANDS;   // 12288
    omnishift_kernel<<<grid, 256, 0, stream>>>(x, w1, w3, w5, alpha, out);
}